// Round 16
// baseline (388.675 us; speedup 1.0000x reference)
//
#include <hip/hip_runtime.h>
#include <hip/hip_bf16.h>
#include <math.h>

// Problem constants
constexpr int Hdim = 768;
constexpr int NH   = 12;
constexpr int HD   = 64;
constexpr int NLAYER = 4;
constexpr int Bb   = 4;
constexpr int Ss   = 1024;
constexpr int Mm   = Bb * Ss;   // 4096 rows
constexpr int NL   = 2;
constexpr int PL   = Bb * NH * Ss;   // 49152 q-rows total
constexpr float LOG2E = 1.44269504088896f;

typedef _Float16 f16x8 __attribute__((ext_vector_type(8)));
typedef _Float16 f16x4 __attribute__((ext_vector_type(4)));
typedef __fp16   h16x2 __attribute__((ext_vector_type(2)));
typedef float    f32x4 __attribute__((ext_vector_type(4)));

__device__ __forceinline__ f32x4 mfma32h(f16x8 a, f16x8 b, f32x4 c) {
#if __has_builtin(__builtin_amdgcn_mfma_f32_16x16x32_f16)
    return __builtin_amdgcn_mfma_f32_16x16x32_f16(a, b, c, 0, 0, 0);
#else
    asm("v_mfma_f32_16x16x32_f16 %0, %1, %2, %0" : "+v"(c) : "v"(a), "v"(b));
    return c;
#endif
}
__device__ __forceinline__ f32x4 mfma16h(f16x4 a, f16x4 b, f32x4 c) {
#if __has_builtin(__builtin_amdgcn_mfma_f32_16x16x16f16)
    return __builtin_amdgcn_mfma_f32_16x16x16f16(a, b, c, 0, 0, 0);
#else
    asm("v_mfma_f32_16x16x16_f16 %0, %1, %2, %0" : "+v"(c) : "v"(a), "v"(b));
    return c;
#endif
}

// async global->LDS, 16B per lane; LDS dest = wave-uniform base + lane*16.
__device__ __forceinline__ void gload16(const void* g, void* l) {
    __builtin_amdgcn_global_load_lds(
        (const __attribute__((address_space(1))) unsigned int*)g,
        (__attribute__((address_space(3))) unsigned int*)l, 16, 0, 0);
}

// ---------------------------------------------------------------------------
// Fused prep: embedding gather (fp16) and all-layer weight fp16 cvt.
// ---------------------------------------------------------------------------
__global__ void prep_kernel(const int* __restrict__ ids,
                            const float* __restrict__ emb,
                            _Float16* __restrict__ xh,
                            const float* __restrict__ Wq, const float* __restrict__ Wk,
                            const float* __restrict__ Wv, const float* __restrict__ Wi,
                            const float* __restrict__ Wo,
                            _Float16* __restrict__ w16) {
    if (blockIdx.x < 3072) {
        int gidx = blockIdx.x * 256 + threadIdx.x;   // 0..786431
        int row = gidx / 192, t = gidx - row * 192;
        int id = ids[row];
        float4 v = ((const float4*)(emb + (size_t)id * Hdim))[t];
        f16x4 h;
        h[0] = (_Float16)v.x; h[1] = (_Float16)v.y;
        h[2] = (_Float16)v.z; h[3] = (_Float16)v.w;
        *(f16x4*)(xh + (size_t)row * Hdim + t * 4) = h;
    } else {
        int i = (blockIdx.x - 3072) * 256 + threadIdx.x;   // 0..2949119
        int l = i / (5 * 147456);
        int rem = i - l * (5 * 147456);
        int which = rem / 147456;
        int j = rem - which * 147456;
        const float* src = (which == 0 ? Wq : which == 1 ? Wk : which == 2 ? Wv
                          : which == 3 ? Wi : Wo) + (size_t)l * 589824;
        float4 v = ((const float4*)src)[j];
        f16x4 h;
        h[0] = (_Float16)v.x; h[1] = (_Float16)v.y;
        h[2] = (_Float16)v.z; h[3] = (_Float16)v.w;
        *(f16x4*)(w16 + ((size_t)l * 5 + which) * 589824 + (size_t)j * 4) = h;
    }
}

// ---------------------------------------------------------------------------
// fp16 MFMA GEMM, BK=64, 256 threads = 4 waves.
// (BM=64, BN=96): wave grid 2x2, wave tile 32x48 (QKV fused N=2304,
//   grid 64x24 = 1536 = exactly 6 blocks/CU).
// (BM=32, BN=128): waves split N 4 ways (Wi/Wo, grid 768 = 3/CU).
// Y32 (if non-null) written only for rows with (row & 1023) == 0 (cls rows).
// 1-D grid with XCD swizzle (nwg % 8 == 0).
// ---------------------------------------------------------------------------
template<int BM, int BN>
__global__ __launch_bounds__(256) void gemm_f16(
    const _Float16* __restrict__ Xh, const _Float16* __restrict__ Wh,
    const float* __restrict__ b0, const float* __restrict__ b1,
    const float* __restrict__ b2,
    const float* __restrict__ resid32,
    _Float16* __restrict__ Yh, float* __restrict__ Y32,
    int relu, size_t outSeg, float qscale, int gm)
{
    constexpr int ABASE = BM * 64;                     // halves
    constexpr int NWN   = (BM == 64) ? 2 : 4;          // waves along N
    constexpr int NFR   = BN / (NWN * 16);             // B fragments per wave
    constexpr int BROWS = BN / 4;                      // B rows staged per wave
    __shared__ _Float16 lds[ABASE + BN * 64];

    const int tid = threadIdx.x;
    const int lane = tid & 63, w = tid >> 6;
    const int l15 = lane & 15, g = lane >> 4;

    // XCD-aware block swizzle (bijective since nwg % 8 == 0)
    const int nwg = gridDim.x;
    const int cpx = nwg >> 3;
    const int bid = blockIdx.x;
    const int x   = (bid & 7) * cpx + (bid >> 3);
    const int m0  = (x % gm) * BM;
    const int n0  = (x / gm) * BN;

    const int srow = lane >> 3;                    // 0..7
    const int sswz = 8 * ((lane & 7) ^ srow);      // swizzled slot (halves)
    const _Float16* pA;
    _Float16* lA;
    if constexpr (BM == 64) {
        pA = Xh + (size_t)(m0 + w*16 + srow) * Hdim + sswz;
        lA = &lds[0] + w * 1024;
    } else {
        pA = Xh + (size_t)(m0 + w*8 + srow) * Hdim + sswz;
        lA = &lds[0] + w * 512;
    }
    const _Float16* pB = Wh + (size_t)(n0 + w*BROWS + srow) * Hdim + sswz;
    _Float16* lB = &lds[ABASE] + w * (BROWS * 64);

    f32x4 acc[2][NFR];
    #pragma unroll
    for (int m = 0; m < 2; ++m)
        #pragma unroll
        for (int n = 0; n < NFR; ++n) acc[m][n] = (f32x4){0.f, 0.f, 0.f, 0.f};

    const int fsw = l15 & 7;

    for (int k0 = 0; k0 < Hdim; k0 += 64) {
        __syncthreads();
        if constexpr (BM == 64) {
            gload16(pA + k0,          lA);
            gload16(pA + k0 + 8*Hdim, lA + 512);
        } else {
            gload16(pA + k0, lA);
        }
        #pragma unroll
        for (int j = 0; j < BROWS / 8; ++j)
            gload16(pB + k0 + j*8*Hdim, lB + j*512);
        __syncthreads();

        #pragma unroll
        for (int ks = 0; ks < 2; ++ks) {
            const int so = 8 * ((ks*4 + g) ^ fsw);
            f16x8 af[2], bf[NFR];
            #pragma unroll
            for (int m = 0; m < 2; ++m) {
                const int ar = (BM == 64) ? ((w >> 1)*32 + m*16 + l15)
                                          : (m*16 + l15);
                af[m] = *(const f16x8*)&lds[ar * 64 + so];
            }
            #pragma unroll
            for (int n = 0; n < NFR; ++n) {
                const int br = (BM == 64) ? ((w & 1)*(NFR*16) + n*16 + l15)
                                          : (w*(NFR*16) + n*16 + l15);
                bf[n] = *(const f16x8*)&lds[ABASE + br * 64 + so];
            }
            #pragma unroll
            for (int m = 0; m < 2; ++m)
                #pragma unroll
                for (int n = 0; n < NFR; ++n)
                    acc[m][n] = mfma32h(af[m], bf[n], acc[m][n]);
        }
    }

    // Epilogue. D layout: col=lane&15, row=(lane>>4)*4+reg.
    const int rb = (BM == 64) ? (m0 + (w >> 1)*32 + g*4) : (m0 + g*4);
    #pragma unroll
    for (int n = 0; n < NFR; ++n) {
        const int col = (BM == 64) ? (n0 + (w & 1)*(NFR*16) + n*16 + l15)
                                   : (n0 + w*(NFR*16) + n*16 + l15);
        const int seg = col / Hdim;
        const int lc  = col - seg * Hdim;
        const float bias = (seg == 0 ? b0 : seg == 1 ? b1 : b2)[lc];
        #pragma unroll
        for (int m = 0; m < 2; ++m) {
            #pragma unroll
            for (int r = 0; r < 4; ++r) {
                const int row = rb + m*16 + r;
                const size_t idx = (size_t)seg * outSeg + (size_t)row * Hdim + lc;
                float v = acc[m][n][r] + bias;
                if (seg == 0) v *= qscale;
                if (relu) v = v > 0.f ? v : 0.f;
                if (resid32) v += resid32[idx];
                Yh[idx] = (_Float16)v;
                if (Y32 && (row & 1023) == 0) Y32[idx] = v;
            }
        }
    }
}

// ---------------------------------------------------------------------------
// fp16 MFMA flash attention partials, KV-split 2-way. Block = 128 q x 512 KV.
// Q pre-scaled by log2e/8 (scores in log2 domain -> native v_exp for exp2).
// K AND V double-buffered -> ONE barrier per tile.
// Writes UNNORMALIZED fp16 O^ partials + fp32 (m, l); merge combines.
// LDS (halves): K0@0 K1@4096 V0@8192 V1@12800 (stride 72) = 34816 B.
// ---------------------------------------------------------------------------
__global__ __launch_bounds__(256, 4) void attn_mfma(
    const _Float16* __restrict__ Qh, const _Float16* __restrict__ Kh,
    const _Float16* __restrict__ Vh,
    _Float16* __restrict__ Op0, _Float16* __restrict__ Op1,
    float* __restrict__ Mp, float* __restrict__ Lp)
{
    __shared__ _Float16 sm[17408];   // 34816 B

    const int tid  = threadIdx.x;
    const int lane = tid & 63, wid = tid >> 6;
    const int l15  = lane & 15, g = lane >> 4;
    const int qtile = blockIdx.x >> 1, part = blockIdx.x & 1;
    const int h = blockIdx.y, b = blockIdx.z;

    const size_t rowbase = (size_t)b * Ss;
    const int    colbase = h * HD;
    const int    q0 = qtile * 128 + wid * 32;
    const int    kv0 = part * 512;

    // Hoisted Q fragments [qfrag][kstep]
    f16x8 qf[2][2];
    #pragma unroll
    for (int nf = 0; nf < 2; ++nf) {
        const size_t r = (rowbase + q0 + nf * 16 + l15) * Hdim + colbase;
        #pragma unroll
        for (int ks = 0; ks < 2; ++ks)
            qf[nf][ks] = *(const f16x8*)(Qh + r + ks * 32 + g * 8);
    }

    f32x4 accO[4][2];
    #pragma unroll
    for (int mf = 0; mf < 4; ++mf)
        #pragma unroll
        for (int nf = 0; nf < 2; ++nf) accO[mf][nf] = (f32x4){0.f, 0.f, 0.f, 0.f};
    float mrun[2] = {-1e30f, -1e30f}, lsum[2] = {0.f, 0.f};

    // K staging constants
    const int s8 = lane >> 3;
    const int kswz = 8 * ((lane & 7) ^ s8);
    const _Float16* gK = Kh + (rowbase + kv0 + wid*16 + s8) * Hdim + colbase + kswz;

    // V staging: wave wid covers cols [wid*16, wid*16+16), lane = KV row.
    const int kx = lane ^ (wid << 4);
    const _Float16* gV = Vh + (rowbase + kv0 + lane) * Hdim + colbase + wid * 16;
    uint4 vr[2];

    const int fsw = l15 & 7;

    // ---- prologue: stage tile 0 into K0/V0 -------------------------------
    gload16(gK,          &sm[0] + wid*1024);
    gload16(gK + 8*Hdim, &sm[0] + wid*1024 + 512);
    #pragma unroll
    for (int u = 0; u < 2; ++u) vr[u] = *(const uint4*)(gV + u * 8);
    #pragma unroll
    for (int u = 0; u < 2; ++u) {
        const _Float16* hs = (const _Float16*)&vr[u];
        #pragma unroll
        for (int j = 0; j < 8; ++j)
            sm[8192 + (wid*16 + u*8 + j) * 72 + kx] = hs[j];
    }
    __syncthreads();

    for (int t = 0; t < 8; ++t) {
        const int cur = t & 1;
        const int kb = cur * 4096;
        const int vb = 8192 + cur * 4608;
        // ---- prefetch tile t+1: K -> off LDS buf, V -> regs --------------
        if (t < 7) {
            const int nkb = (cur ^ 1) * 4096;
            const size_t ko = (size_t)((t + 1) * 64) * Hdim;
            gload16(gK + ko,          &sm[nkb] + wid*1024);
            gload16(gK + ko + 8*Hdim, &sm[nkb] + wid*1024 + 512);
            #pragma unroll
            for (int u = 0; u < 2; ++u)
                vr[u] = *(const uint4*)(gV + ko + u * 8);
        }

        // ---- S^T = K · Q^T (fp16 single-term; log2-domain scores) --------
        f32x4 sc[4][2];
        #pragma unroll
        for (int m = 0; m < 4; ++m)
            #pragma unroll
            for (int nf = 0; nf < 2; ++nf) sc[m][nf] = (f32x4){0.f, 0.f, 0.f, 0.f};
        __builtin_amdgcn_s_setprio(1);
        #pragma unroll
        for (int ks = 0; ks < 2; ++ks) {
            const int so = 8 * ((ks*4 + g) ^ fsw);
            #pragma unroll
            for (int m = 0; m < 4; ++m) {
                f16x8 kh_ = *(const f16x8*)&sm[kb + (m * 16 + l15) * 64 + so];
                #pragma unroll
                for (int nf = 0; nf < 2; ++nf)
                    sc[m][nf] = mfma32h(kh_, qf[nf][ks], sc[m][nf]);
            }
        }
        __builtin_amdgcn_s_setprio(0);

        // ---- online softmax (exp2 domain, defer-max) ---------------------
        f16x4 pb[4][2];
        #pragma unroll
        for (int nf = 0; nf < 2; ++nf) {
            float tl = -1e30f;
            #pragma unroll
            for (int m = 0; m < 4; ++m)
                #pragma unroll
                for (int r = 0; r < 4; ++r) tl = fmaxf(tl, sc[m][nf][r]);
            if (__any(tl > mrun[nf] + 11.5416f)) {       // 8 nats in log2 units
                float tmax = fmaxf(tl, __shfl_xor(tl, 16));
                tmax = fmaxf(tmax, __shfl_xor(tmax, 32));
                const float mnew = fmaxf(mrun[nf], tmax);
                const float corr = __builtin_amdgcn_exp2f(mrun[nf] - mnew);
                mrun[nf] = mnew;
                lsum[nf] *= corr;
                #pragma unroll
                for (int mf = 0; mf < 4; ++mf) {
                    accO[mf][nf][0] *= corr; accO[mf][nf][1] *= corr;
                    accO[mf][nf][2] *= corr; accO[mf][nf][3] *= corr;
                }
            }
            float ps = 0.f;
            #pragma unroll
            for (int m = 0; m < 4; ++m)
                #pragma unroll
                for (int r = 0; r < 4; ++r) {
                    const float p = __builtin_amdgcn_exp2f(sc[m][nf][r] - mrun[nf]);
                    sc[m][nf][r] = p;
                    ps += p;
                }
            lsum[nf] += ps;
            #pragma unroll
            for (int kt = 0; kt < 4; ++kt) {
                union { h16x2 h2[2]; f16x4 v; } u;
                u.h2[0] = __builtin_amdgcn_cvt_pkrtz(sc[kt][nf][0], sc[kt][nf][1]);
                u.h2[1] = __builtin_amdgcn_cvt_pkrtz(sc[kt][nf][2], sc[kt][nf][3]);
                pb[kt][nf] = u.v;
            }
        }

        // ---- write V(t+1) into the off buffer ----------------------------
        if (t < 7) {
            const int nvb = 8192 + (cur ^ 1) * 4608;
            #pragma unroll
            for (int u = 0; u < 2; ++u) {
                const _Float16* hs = (const _Float16*)&vr[u];
                #pragma unroll
                for (int j = 0; j < 8; ++j)
                    sm[nvb + (wid*16 + u*8 + j) * 72 + kx] = hs[j];
            }
        }

        // ---- O^T += V^T · P^T (fp16 single-term) -------------------------
        __builtin_amdgcn_s_setprio(1);
        #pragma unroll
        for (int kt = 0; kt < 4; ++kt)
            #pragma unroll
            for (int mf = 0; mf < 4; ++mf) {
                const int voff = vb + (mf * 16 + l15) * 72 + ((kt ^ mf) * 16 + g * 4);
                f16x4 vh_ = *(const f16x4*)&sm[voff];
                #pragma unroll
                for (int nf = 0; nf < 2; ++nf)
                    accO[mf][nf] = mfma16h(vh_, pb[kt][nf], accO[mf][nf]);
            }
        __builtin_amdgcn_s_setprio(0);

        __syncthreads();   // drains K(t+1) gloads; publishes V(t+1)
    }

    // ---- epilogue: reduce l; transpose O^ as fp16 through LDS ------------
    #pragma unroll
    for (int nf = 0; nf < 2; ++nf) {
        lsum[nf] += __shfl_xor(lsum[nf], 16);
        lsum[nf] += __shfl_xor(lsum[nf], 32);
    }
    __syncthreads();
    _Float16* ot16 = (_Float16*)sm + wid * 2304;   // 32 rows x stride 72
    #pragma unroll
    for (int nf = 0; nf < 2; ++nf)
        #pragma unroll
        for (int mf = 0; mf < 4; ++mf) {
            union { h16x2 h2[2]; f16x4 v; } u;
            u.h2[0] = __builtin_amdgcn_cvt_pkrtz(accO[mf][nf][0], accO[mf][nf][1]);
            u.h2[1] = __builtin_amdgcn_cvt_pkrtz(accO[mf][nf][2], accO[mf][nf][3]);
            *(f16x4*)&ot16[(nf * 16 + l15) * 72 + mf * 16 + g * 4] = u.v;
        }
    if (g == 0) {
        #pragma unroll
        for (int nf = 0; nf < 2; ++nf) {
            const size_t idx = (size_t)part * PL +
                (((size_t)b * NH + h) * Ss + q0 + nf * 16 + l15);
            Mp[idx] = mrun[nf];
            Lp[idx] = lsum[nf];
        }
    }
    __syncthreads();
    _Float16* Op = part ? Op1 : Op0;
    const int orow = lane >> 1, oc = (lane & 1) * 32;
    const size_t pbase = (((size_t)b * NH + h) * Ss + q0 + orow) * 64 + oc;
    #pragma unroll
    for (int i = 0; i < 4; ++i)
        *(f16x8*)(Op + pbase + i * 8) = *(const f16x8*)&ot16[orow * 72 + oc + i * 8];
}

// ---------------------------------------------------------------------------
// Merge the two KV-split fp16 partials -> attn output (fp16 for Wi, fp32
// residual for Wo). m values are in log2 domain.
// ---------------------------------------------------------------------------
__global__ void merge_kernel(const _Float16* __restrict__ Op0,
                             const _Float16* __restrict__ Op1,
                             const float* __restrict__ Mp, const float* __restrict__ Lp,
                             _Float16* __restrict__ a16, float* __restrict__ a32) {
    const int id = blockIdx.x * 256 + threadIdx.x;   // 0..196607
    const int idx = id >> 2, dseg = id & 3;
    const int b = idx / (NH * Ss);
    const int rem = idx - b * NH * Ss;
    const int h = rem / Ss, q = rem - h * Ss;
    const float m0 = Mp[idx], m1 = Mp[PL + idx];
    const float l0 = Lp[idx], l1 = Lp[PL + idx];
    const float M  = fmaxf(m0, m1);
    const float e0 = __builtin_amdgcn_exp2f(m0 - M);
    const float e1 = __builtin_amdgcn_exp2f(m1 - M);
    const float inv = 1.f / (l0 * e0 + l1 * e1);
    const float s0 = e0 * inv, s1 = e1 * inv;
    const size_t pb = (size_t)idx * 64 + dseg * 16;
    const size_t ga = ((size_t)(b * Ss + q)) * Hdim + h * 64 + dseg * 16;
    #pragma unroll
    for (int i = 0; i < 2; ++i) {
        f16x8 a = *(const f16x8*)(Op0 + pb + i * 8);
        f16x8 c = *(const f16x8*)(Op1 + pb + i * 8);
        f16x8 ho;
        float ov[8];
        #pragma unroll
        for (int j = 0; j < 8; ++j) {
            const float v = (float)a[j] * s0 + (float)c[j] * s1;
            ov[j] = v;
            ho[j] = (_Float16)v;
        }
        *(f16x8*)(a16 + ga + i * 8) = ho;
        float4 q0 = make_float4(ov[0], ov[1], ov[2], ov[3]);
        float4 q1 = make_float4(ov[4], ov[5], ov[6], ov[7]);
        *(float4*)(a32 + ga + i * 8)     = q0;
        *(float4*)(a32 + ga + i * 8 + 4) = q1;
    }
}

// ---------------------------------------------------------------------------
// Classifier: logits[b,n] = dot(x32[b,0,:], Wc[n,:]) + bc[n]
// ---------------------------------------------------------------------------
__global__ void cls_kernel(const float* __restrict__ x32,
                           const float* __restrict__ Wc,
                           const float* __restrict__ bc,
                           float* __restrict__ out) {
    const int b = blockIdx.x >> 1;
    const int n = blockIdx.x & 1;
    const int t = threadIdx.x;
    const float* px = x32 + (size_t)b * Ss * Hdim;   // row s=0
    const float* pw = Wc + (size_t)n * Hdim;
    float partial = 0.f;
    for (int k = t; k < Hdim; k += 256) partial = fmaf(px[k], pw[k], partial);
    __shared__ float red[256];
    red[t] = partial;
    __syncthreads();
    for (int off = 128; off > 0; off >>= 1) {
        if (t < off) red[t] += red[t + off];
        __syncthreads();
    }
    if (t == 0) out[blockIdx.x] = red[0] + bc[n];
}

// ---------------------------------------------------------------------------
extern "C" void kernel_launch(void* const* d_in, const int* in_sizes, int n_in,
                              void* d_out, int out_size, void* d_ws, size_t ws_size,
                              hipStream_t stream) {
    const int*   ids = (const int*)d_in[0];
    const float* emb = (const float*)d_in[1];
    const float* Wq  = (const float*)d_in[2];
    const float* bq  = (const float*)d_in[3];
    const float* Wk  = (const float*)d_in[4];
    const float* bk  = (const float*)d_in[5];
    const float* Wv  = (const float*)d_in[6];
    const float* bv  = (const float*)d_in[7];
    const float* Wi  = (const float*)d_in[8];
    const float* bi  = (const float*)d_in[9];
    const float* Wo  = (const float*)d_in[10];
    const float* bo  = (const float*)d_in[11];
    const float* Wc  = (const float*)d_in[12];
    const float* bc  = (const float*)d_in[13];
    float* out = (float*)d_out;

    const size_t F  = (size_t)Mm * Hdim;      // 3,145,728
    const size_t WS = (size_t)Hdim * Hdim;    // 589,824

    float*    x32 = (float*)d_ws;             // cls input (rows s=0 only)
    _Float16* xh  = (_Float16*)(x32 + F);     // fp16 stream
    _Float16* qkv = xh + F;                   // 3F fp16
    _Float16* a16 = qkv + 3 * F;              // attn out fp16
    _Float16* i16 = a16 + F;                  // inter fp16
    _Float16* w16 = i16 + F;                  // ALL layers' weights fp16 (20*WS)
    _Float16* Op0 = w16 + 20 * WS;            // fp16 unnormalized partials
    _Float16* Op1 = Op0 + F;
    float*    a32 = (float*)(Op1 + F);        // attn out fp32 (Wo residual)
    float*    Mp  = a32 + F;                  // [2][PL]
    float*    Lp  = Mp + 2 * PL;              // [2][PL]

    prep_kernel<<<14592, 256, 0, stream>>>(ids, emb, xh, Wq, Wk, Wv, Wi, Wo, w16);

    for (int l = 0; l < NLAYER; ++l) {
        _Float16* wl = w16 + (size_t)l * 5 * WS;
        // fused QKV: W rows 0..2303 = Wq|Wk|Wv (contiguous in wl)
        gemm_f16<64, 96><<<1536, 256, 0, stream>>>(
            xh, wl, bq + l*Hdim, bk + l*Hdim, bv + l*Hdim,
            nullptr, qkv, nullptr, 0, F, 0.125f * LOG2E, 64);
        attn_mfma<<<dim3(16, NH, Bb), 256, 0, stream>>>(
            qkv, qkv + F, qkv + 2*F, Op0, Op1, Mp, Lp);
        merge_kernel<<<PL * 4 / 256, 256, 0, stream>>>(Op0, Op1, Mp, Lp, a16, a32);
        gemm_f16<32, 128><<<768, 256, 0, stream>>>(
            a16, wl + 3*WS, bi + l*Hdim, bi + l*Hdim, bi + l*Hdim,
            nullptr, i16, nullptr, 1, 0, 1.f, 128);
        gemm_f16<32, 128><<<768, 256, 0, stream>>>(
            i16, wl + 4*WS, bo + l*Hdim, bo + l*Hdim, bo + l*Hdim,
            a32, xh, (l == NLAYER - 1) ? x32 : nullptr, 0, 0, 1.f, 128);
    }

    cls_kernel<<<Bb * NL, 256, 0, stream>>>(x32, Wc, bc, out);
}

// Round 17
// 381.580 us; speedup vs baseline: 1.0186x; 1.0186x over previous
//
#include <hip/hip_runtime.h>
#include <hip/hip_bf16.h>
#include <math.h>

// Problem constants
constexpr int Hdim = 768;
constexpr int NH   = 12;
constexpr int HD   = 64;
constexpr int NLAYER = 4;
constexpr int Bb   = 4;
constexpr int Ss   = 1024;
constexpr int Mm   = Bb * Ss;   // 4096 rows
constexpr int NL   = 2;
constexpr int PL   = Bb * NH * Ss;   // 49152 q-rows total
constexpr float LOG2E = 1.44269504088896f;

typedef _Float16 f16x8 __attribute__((ext_vector_type(8)));
typedef _Float16 f16x4 __attribute__((ext_vector_type(4)));
typedef __fp16   h16x2 __attribute__((ext_vector_type(2)));
typedef float    f32x4 __attribute__((ext_vector_type(4)));

__device__ __forceinline__ f32x4 mfma32h(f16x8 a, f16x8 b, f32x4 c) {
#if __has_builtin(__builtin_amdgcn_mfma_f32_16x16x32_f16)
    return __builtin_amdgcn_mfma_f32_16x16x32_f16(a, b, c, 0, 0, 0);
#else
    asm("v_mfma_f32_16x16x32_f16 %0, %1, %2, %0" : "+v"(c) : "v"(a), "v"(b));
    return c;
#endif
}
__device__ __forceinline__ f32x4 mfma16h(f16x4 a, f16x4 b, f32x4 c) {
#if __has_builtin(__builtin_amdgcn_mfma_f32_16x16x16f16)
    return __builtin_amdgcn_mfma_f32_16x16x16f16(a, b, c, 0, 0, 0);
#else
    asm("v_mfma_f32_16x16x16_f16 %0, %1, %2, %0" : "+v"(c) : "v"(a), "v"(b));
    return c;
#endif
}

// async global->LDS, 16B per lane; LDS dest = wave-uniform base + lane*16.
__device__ __forceinline__ void gload16(const void* g, void* l) {
    __builtin_amdgcn_global_load_lds(
        (const __attribute__((address_space(1))) unsigned int*)g,
        (__attribute__((address_space(3))) unsigned int*)l, 16, 0, 0);
}

// ---------------------------------------------------------------------------
// Fused prep: embedding gather (fp16) and all-layer weight fp16 cvt.
// ---------------------------------------------------------------------------
__global__ void prep_kernel(const int* __restrict__ ids,
                            const float* __restrict__ emb,
                            _Float16* __restrict__ xh,
                            const float* __restrict__ Wq, const float* __restrict__ Wk,
                            const float* __restrict__ Wv, const float* __restrict__ Wi,
                            const float* __restrict__ Wo,
                            _Float16* __restrict__ w16) {
    if (blockIdx.x < 3072) {
        int gidx = blockIdx.x * 256 + threadIdx.x;   // 0..786431
        int row = gidx / 192, t = gidx - row * 192;
        int id = ids[row];
        float4 v = ((const float4*)(emb + (size_t)id * Hdim))[t];
        f16x4 h;
        h[0] = (_Float16)v.x; h[1] = (_Float16)v.y;
        h[2] = (_Float16)v.z; h[3] = (_Float16)v.w;
        *(f16x4*)(xh + (size_t)row * Hdim + t * 4) = h;
    } else {
        int i = (blockIdx.x - 3072) * 256 + threadIdx.x;   // 0..2949119
        int l = i / (5 * 147456);
        int rem = i - l * (5 * 147456);
        int which = rem / 147456;
        int j = rem - which * 147456;
        const float* src = (which == 0 ? Wq : which == 1 ? Wk : which == 2 ? Wv
                          : which == 3 ? Wi : Wo) + (size_t)l * 589824;
        float4 v = ((const float4*)src)[j];
        f16x4 h;
        h[0] = (_Float16)v.x; h[1] = (_Float16)v.y;
        h[2] = (_Float16)v.z; h[3] = (_Float16)v.w;
        *(f16x4*)(w16 + ((size_t)l * 5 + which) * 589824 + (size_t)j * 4) = h;
    }
}

// ---------------------------------------------------------------------------
// fp16 MFMA GEMM, BK=64, 256 threads = 4 waves, BN=128.
// BM=64: wave grid 2x2 (QKV fused N=2304, grid 1152).
// BM=32: waves split N 4 ways (Wi/Wo, grid 768 = 3/CU).
// Y32 (if non-null) written only for rows with (row & 1023) == 0 (cls rows).
// 1-D grid with XCD swizzle (nwg % 8 == 0).
// ---------------------------------------------------------------------------
template<int BM>
__global__ __launch_bounds__(256) void gemm_f16(
    const _Float16* __restrict__ Xh, const _Float16* __restrict__ Wh,
    const float* __restrict__ b0, const float* __restrict__ b1,
    const float* __restrict__ b2,
    const float* __restrict__ resid32,
    _Float16* __restrict__ Yh, float* __restrict__ Y32,
    int relu, size_t outSeg, float qscale, int gm)
{
    constexpr int ABASE = BM * 64;            // halves
    constexpr int NFR   = (BM == 64) ? 4 : 2; // B fragments per wave
    __shared__ _Float16 lds[ABASE + 8192];

    const int tid = threadIdx.x;
    const int lane = tid & 63, w = tid >> 6;
    const int l15 = lane & 15, g = lane >> 4;

    // XCD-aware block swizzle (bijective since nwg % 8 == 0)
    const int nwg = gridDim.x;
    const int cpx = nwg >> 3;
    const int bid = blockIdx.x;
    const int x   = (bid & 7) * cpx + (bid >> 3);
    const int m0  = (x % gm) * BM;
    const int n0  = (x / gm) * 128;

    const int srow = lane >> 3;                    // 0..7
    const int sswz = 8 * ((lane & 7) ^ srow);      // swizzled slot (halves)
    const _Float16* pA;
    _Float16* lA;
    if constexpr (BM == 64) {
        pA = Xh + (size_t)(m0 + w*16 + srow) * Hdim + sswz;
        lA = &lds[0] + w * 1024;
    } else {
        pA = Xh + (size_t)(m0 + w*8 + srow) * Hdim + sswz;
        lA = &lds[0] + w * 512;
    }
    const _Float16* pB = Wh + (size_t)(n0 + w*32 + srow) * Hdim + sswz;
    _Float16* lB = &lds[ABASE] + w * 2048;

    f32x4 acc[2][NFR];
    #pragma unroll
    for (int m = 0; m < 2; ++m)
        #pragma unroll
        for (int n = 0; n < NFR; ++n) acc[m][n] = (f32x4){0.f, 0.f, 0.f, 0.f};

    const int fsw = l15 & 7;

    for (int k0 = 0; k0 < Hdim; k0 += 64) {
        __syncthreads();
        if constexpr (BM == 64) {
            gload16(pA + k0,          lA);
            gload16(pA + k0 + 8*Hdim, lA + 512);
        } else {
            gload16(pA + k0, lA);
        }
        #pragma unroll
        for (int j = 0; j < 4; ++j)
            gload16(pB + k0 + j*8*Hdim, lB + j*512);
        __syncthreads();

        #pragma unroll
        for (int ks = 0; ks < 2; ++ks) {
            const int so = 8 * ((ks*4 + g) ^ fsw);
            f16x8 af[2], bf[NFR];
            #pragma unroll
            for (int m = 0; m < 2; ++m) {
                const int ar = (BM == 64) ? ((w >> 1)*32 + m*16 + l15)
                                          : (m*16 + l15);
                af[m] = *(const f16x8*)&lds[ar * 64 + so];
            }
            #pragma unroll
            for (int n = 0; n < NFR; ++n) {
                const int br = (BM == 64) ? ((w & 1)*64 + n*16 + l15)
                                          : (w*32 + n*16 + l15);
                bf[n] = *(const f16x8*)&lds[ABASE + br * 64 + so];
            }
            #pragma unroll
            for (int m = 0; m < 2; ++m)
                #pragma unroll
                for (int n = 0; n < NFR; ++n)
                    acc[m][n] = mfma32h(af[m], bf[n], acc[m][n]);
        }
    }

    // Epilogue. D layout: col=lane&15, row=(lane>>4)*4+reg.
    const int rb = (BM == 64) ? (m0 + (w >> 1)*32 + g*4) : (m0 + g*4);
    #pragma unroll
    for (int n = 0; n < NFR; ++n) {
        const int col = (BM == 64) ? (n0 + (w & 1)*64 + n*16 + l15)
                                   : (n0 + w*32 + n*16 + l15);
        const int seg = col / Hdim;
        const int lc  = col - seg * Hdim;
        const float bias = (seg == 0 ? b0 : seg == 1 ? b1 : b2)[lc];
        #pragma unroll
        for (int m = 0; m < 2; ++m) {
            #pragma unroll
            for (int r = 0; r < 4; ++r) {
                const int row = rb + m*16 + r;
                const size_t idx = (size_t)seg * outSeg + (size_t)row * Hdim + lc;
                float v = acc[m][n][r] + bias;
                if (seg == 0) v *= qscale;
                if (relu) v = v > 0.f ? v : 0.f;
                if (resid32) v += resid32[idx];
                Yh[idx] = (_Float16)v;
                if (Y32 && (row & 1023) == 0) Y32[idx] = v;
            }
        }
    }
}

// ---------------------------------------------------------------------------
// fp16 MFMA flash attention partials, KV-split 2-way. Block = 128 q x 512 KV.
// Q pre-scaled by log2e/8 (scores in log2 domain -> native v_exp for exp2).
// K AND V double-buffered -> ONE barrier per tile.
// Writes UNNORMALIZED fp16 O^ partials + fp32 (m, l); merge combines.
// LDS (halves): K0@0 K1@4096 V0@8192 V1@12800 (stride 72) = 34816 B.
// ---------------------------------------------------------------------------
__global__ __launch_bounds__(256, 4) void attn_mfma(
    const _Float16* __restrict__ Qh, const _Float16* __restrict__ Kh,
    const _Float16* __restrict__ Vh,
    _Float16* __restrict__ Op0, _Float16* __restrict__ Op1,
    float* __restrict__ Mp, float* __restrict__ Lp)
{
    __shared__ _Float16 sm[17408];   // 34816 B

    const int tid  = threadIdx.x;
    const int lane = tid & 63, wid = tid >> 6;
    const int l15  = lane & 15, g = lane >> 4;
    const int qtile = blockIdx.x >> 1, part = blockIdx.x & 1;
    const int h = blockIdx.y, b = blockIdx.z;

    const size_t rowbase = (size_t)b * Ss;
    const int    colbase = h * HD;
    const int    q0 = qtile * 128 + wid * 32;
    const int    kv0 = part * 512;

    // Hoisted Q fragments [qfrag][kstep]
    f16x8 qf[2][2];
    #pragma unroll
    for (int nf = 0; nf < 2; ++nf) {
        const size_t r = (rowbase + q0 + nf * 16 + l15) * Hdim + colbase;
        #pragma unroll
        for (int ks = 0; ks < 2; ++ks)
            qf[nf][ks] = *(const f16x8*)(Qh + r + ks * 32 + g * 8);
    }

    f32x4 accO[4][2];
    #pragma unroll
    for (int mf = 0; mf < 4; ++mf)
        #pragma unroll
        for (int nf = 0; nf < 2; ++nf) accO[mf][nf] = (f32x4){0.f, 0.f, 0.f, 0.f};
    float mrun[2] = {-1e30f, -1e30f}, lsum[2] = {0.f, 0.f};

    // K staging constants
    const int s8 = lane >> 3;
    const int kswz = 8 * ((lane & 7) ^ s8);
    const _Float16* gK = Kh + (rowbase + kv0 + wid*16 + s8) * Hdim + colbase + kswz;

    // V staging: wave wid covers cols [wid*16, wid*16+16), lane = KV row.
    const int kx = lane ^ (wid << 4);
    const _Float16* gV = Vh + (rowbase + kv0 + lane) * Hdim + colbase + wid * 16;
    uint4 vr[2];

    const int fsw = l15 & 7;

    // ---- prologue: stage tile 0 into K0/V0 -------------------------------
    gload16(gK,          &sm[0] + wid*1024);
    gload16(gK + 8*Hdim, &sm[0] + wid*1024 + 512);
    #pragma unroll
    for (int u = 0; u < 2; ++u) vr[u] = *(const uint4*)(gV + u * 8);
    #pragma unroll
    for (int u = 0; u < 2; ++u) {
        const _Float16* hs = (const _Float16*)&vr[u];
        #pragma unroll
        for (int j = 0; j < 8; ++j)
            sm[8192 + (wid*16 + u*8 + j) * 72 + kx] = hs[j];
    }
    __syncthreads();

    for (int t = 0; t < 8; ++t) {
        const int cur = t & 1;
        const int kb = cur * 4096;
        const int vb = 8192 + cur * 4608;
        // ---- prefetch tile t+1: K -> off LDS buf, V -> regs --------------
        if (t < 7) {
            const int nkb = (cur ^ 1) * 4096;
            const size_t ko = (size_t)((t + 1) * 64) * Hdim;
            gload16(gK + ko,          &sm[nkb] + wid*1024);
            gload16(gK + ko + 8*Hdim, &sm[nkb] + wid*1024 + 512);
            #pragma unroll
            for (int u = 0; u < 2; ++u)
                vr[u] = *(const uint4*)(gV + ko + u * 8);
        }

        // ---- S^T = K · Q^T (fp16 single-term; log2-domain scores) --------
        f32x4 sc[4][2];
        #pragma unroll
        for (int m = 0; m < 4; ++m)
            #pragma unroll
            for (int nf = 0; nf < 2; ++nf) sc[m][nf] = (f32x4){0.f, 0.f, 0.f, 0.f};
        __builtin_amdgcn_s_setprio(1);
        #pragma unroll
        for (int ks = 0; ks < 2; ++ks) {
            const int so = 8 * ((ks*4 + g) ^ fsw);
            #pragma unroll
            for (int m = 0; m < 4; ++m) {
                f16x8 kh_ = *(const f16x8*)&sm[kb + (m * 16 + l15) * 64 + so];
                #pragma unroll
                for (int nf = 0; nf < 2; ++nf)
                    sc[m][nf] = mfma32h(kh_, qf[nf][ks], sc[m][nf]);
            }
        }
        __builtin_amdgcn_s_setprio(0);

        // ---- online softmax (exp2 domain, defer-max) ---------------------
        f16x4 pb[4][2];
        #pragma unroll
        for (int nf = 0; nf < 2; ++nf) {
            float tl = -1e30f;
            #pragma unroll
            for (int m = 0; m < 4; ++m)
                #pragma unroll
                for (int r = 0; r < 4; ++r) tl = fmaxf(tl, sc[m][nf][r]);
            if (__any(tl > mrun[nf] + 11.5416f)) {       // 8 nats in log2 units
                float tmax = fmaxf(tl, __shfl_xor(tl, 16));
                tmax = fmaxf(tmax, __shfl_xor(tmax, 32));
                const float mnew = fmaxf(mrun[nf], tmax);
                const float corr = __builtin_amdgcn_exp2f(mrun[nf] - mnew);
                mrun[nf] = mnew;
                lsum[nf] *= corr;
                #pragma unroll
                for (int mf = 0; mf < 4; ++mf) {
                    accO[mf][nf][0] *= corr; accO[mf][nf][1] *= corr;
                    accO[mf][nf][2] *= corr; accO[mf][nf][3] *= corr;
                }
            }
            float ps = 0.f;
            #pragma unroll
            for (int m = 0; m < 4; ++m)
                #pragma unroll
                for (int r = 0; r < 4; ++r) {
                    const float p = __builtin_amdgcn_exp2f(sc[m][nf][r] - mrun[nf]);
                    sc[m][nf][r] = p;
                    ps += p;
                }
            lsum[nf] += ps;
            #pragma unroll
            for (int kt = 0; kt < 4; ++kt) {
                union { h16x2 h2[2]; f16x4 v; } u;
                u.h2[0] = __builtin_amdgcn_cvt_pkrtz(sc[kt][nf][0], sc[kt][nf][1]);
                u.h2[1] = __builtin_amdgcn_cvt_pkrtz(sc[kt][nf][2], sc[kt][nf][3]);
                pb[kt][nf] = u.v;
            }
        }

        // ---- write V(t+1) into the off buffer ----------------------------
        if (t < 7) {
            const int nvb = 8192 + (cur ^ 1) * 4608;
            #pragma unroll
            for (int u = 0; u < 2; ++u) {
                const _Float16* hs = (const _Float16*)&vr[u];
                #pragma unroll
                for (int j = 0; j < 8; ++j)
                    sm[nvb + (wid*16 + u*8 + j) * 72 + kx] = hs[j];
            }
        }

        // ---- O^T += V^T · P^T (fp16 single-term) -------------------------
        __builtin_amdgcn_s_setprio(1);
        #pragma unroll
        for (int kt = 0; kt < 4; ++kt)
            #pragma unroll
            for (int mf = 0; mf < 4; ++mf) {
                const int voff = vb + (mf * 16 + l15) * 72 + ((kt ^ mf) * 16 + g * 4);
                f16x4 vh_ = *(const f16x4*)&sm[voff];
                #pragma unroll
                for (int nf = 0; nf < 2; ++nf)
                    accO[mf][nf] = mfma16h(vh_, pb[kt][nf], accO[mf][nf]);
            }
        __builtin_amdgcn_s_setprio(0);

        __syncthreads();   // drains K(t+1) gloads; publishes V(t+1)
    }

    // ---- epilogue: reduce l; transpose O^ as fp16 through LDS ------------
    #pragma unroll
    for (int nf = 0; nf < 2; ++nf) {
        lsum[nf] += __shfl_xor(lsum[nf], 16);
        lsum[nf] += __shfl_xor(lsum[nf], 32);
    }
    __syncthreads();
    _Float16* ot16 = (_Float16*)sm + wid * 2304;   // 32 rows x stride 72
    #pragma unroll
    for (int nf = 0; nf < 2; ++nf)
        #pragma unroll
        for (int mf = 0; mf < 4; ++mf) {
            union { h16x2 h2[2]; f16x4 v; } u;
            u.h2[0] = __builtin_amdgcn_cvt_pkrtz(accO[mf][nf][0], accO[mf][nf][1]);
            u.h2[1] = __builtin_amdgcn_cvt_pkrtz(accO[mf][nf][2], accO[mf][nf][3]);
            *(f16x4*)&ot16[(nf * 16 + l15) * 72 + mf * 16 + g * 4] = u.v;
        }
    if (g == 0) {
        #pragma unroll
        for (int nf = 0; nf < 2; ++nf) {
            const size_t idx = (size_t)part * PL +
                (((size_t)b * NH + h) * Ss + q0 + nf * 16 + l15);
            Mp[idx] = mrun[nf];
            Lp[idx] = lsum[nf];
        }
    }
    __syncthreads();
    _Float16* Op = part ? Op1 : Op0;
    const int orow = lane >> 1, oc = (lane & 1) * 32;
    const size_t pbase = (((size_t)b * NH + h) * Ss + q0 + orow) * 64 + oc;
    #pragma unroll
    for (int i = 0; i < 4; ++i)
        *(f16x8*)(Op + pbase + i * 8) = *(const f16x8*)&ot16[orow * 72 + oc + i * 8];
}

// ---------------------------------------------------------------------------
// Merge the two KV-split fp16 partials -> attn output (fp16 for Wi, fp32
// residual for Wo). m values are in log2 domain.
// ---------------------------------------------------------------------------
__global__ void merge_kernel(const _Float16* __restrict__ Op0,
                             const _Float16* __restrict__ Op1,
                             const float* __restrict__ Mp, const float* __restrict__ Lp,
                             _Float16* __restrict__ a16, float* __restrict__ a32) {
    const int id = blockIdx.x * 256 + threadIdx.x;   // 0..196607
    const int idx = id >> 2, dseg = id & 3;
    const int b = idx / (NH * Ss);
    const int rem = idx - b * NH * Ss;
    const int h = rem / Ss, q = rem - h * Ss;
    const float m0 = Mp[idx], m1 = Mp[PL + idx];
    const float l0 = Lp[idx], l1 = Lp[PL + idx];
    const float M  = fmaxf(m0, m1);
    const float e0 = __builtin_amdgcn_exp2f(m0 - M);
    const float e1 = __builtin_amdgcn_exp2f(m1 - M);
    const float inv = 1.f / (l0 * e0 + l1 * e1);
    const float s0 = e0 * inv, s1 = e1 * inv;
    const size_t pb = (size_t)idx * 64 + dseg * 16;
    const size_t ga = ((size_t)(b * Ss + q)) * Hdim + h * 64 + dseg * 16;
    #pragma unroll
    for (int i = 0; i < 2; ++i) {
        f16x8 a = *(const f16x8*)(Op0 + pb + i * 8);
        f16x8 c = *(const f16x8*)(Op1 + pb + i * 8);
        f16x8 ho;
        float ov[8];
        #pragma unroll
        for (int j = 0; j < 8; ++j) {
            const float v = (float)a[j] * s0 + (float)c[j] * s1;
            ov[j] = v;
            ho[j] = (_Float16)v;
        }
        *(f16x8*)(a16 + ga + i * 8) = ho;
        float4 q0 = make_float4(ov[0], ov[1], ov[2], ov[3]);
        float4 q1 = make_float4(ov[4], ov[5], ov[6], ov[7]);
        *(float4*)(a32 + ga + i * 8)     = q0;
        *(float4*)(a32 + ga + i * 8 + 4) = q1;
    }
}

// ---------------------------------------------------------------------------
// Classifier: logits[b,n] = dot(x32[b,0,:], Wc[n,:]) + bc[n]
// ---------------------------------------------------------------------------
__global__ void cls_kernel(const float* __restrict__ x32,
                           const float* __restrict__ Wc,
                           const float* __restrict__ bc,
                           float* __restrict__ out) {
    const int b = blockIdx.x >> 1;
    const int n = blockIdx.x & 1;
    const int t = threadIdx.x;
    const float* px = x32 + (size_t)b * Ss * Hdim;   // row s=0
    const float* pw = Wc + (size_t)n * Hdim;
    float partial = 0.f;
    for (int k = t; k < Hdim; k += 256) partial = fmaf(px[k], pw[k], partial);
    __shared__ float red[256];
    red[t] = partial;
    __syncthreads();
    for (int off = 128; off > 0; off >>= 1) {
        if (t < off) red[t] += red[t + off];
        __syncthreads();
    }
    if (t == 0) out[blockIdx.x] = red[0] + bc[n];
}

// ---------------------------------------------------------------------------
extern "C" void kernel_launch(void* const* d_in, const int* in_sizes, int n_in,
                              void* d_out, int out_size, void* d_ws, size_t ws_size,
                              hipStream_t stream) {
    const int*   ids = (const int*)d_in[0];
    const float* emb = (const float*)d_in[1];
    const float* Wq  = (const float*)d_in[2];
    const float* bq  = (const float*)d_in[3];
    const float* Wk  = (const float*)d_in[4];
    const float* bk  = (const float*)d_in[5];
    const float* Wv  = (const float*)d_in[6];
    const float* bv  = (const float*)d_in[7];
    const float* Wi  = (const float*)d_in[8];
    const float* bi  = (const float*)d_in[9];
    const float* Wo  = (const float*)d_in[10];
    const float* bo  = (const float*)d_in[11];
    const float* Wc  = (const float*)d_in[12];
    const float* bc  = (const float*)d_in[13];
    float* out = (float*)d_out;

    const size_t F  = (size_t)Mm * Hdim;      // 3,145,728
    const size_t WS = (size_t)Hdim * Hdim;    // 589,824

    float*    x32 = (float*)d_ws;             // cls input (rows s=0 only)
    _Float16* xh  = (_Float16*)(x32 + F);     // fp16 stream
    _Float16* qkv = xh + F;                   // 3F fp16
    _Float16* a16 = qkv + 3 * F;              // attn out fp16
    _Float16* i16 = a16 + F;                  // inter fp16
    _Float16* w16 = i16 + F;                  // ALL layers' weights fp16 (20*WS)
    _Float16* Op0 = w16 + 20 * WS;            // fp16 unnormalized partials
    _Float16* Op1 = Op0 + F;
    float*    a32 = (float*)(Op1 + F);        // attn out fp32 (Wo residual)
    float*    Mp  = a32 + F;                  // [2][PL]
    float*    Lp  = Mp + 2 * PL;              // [2][PL]

    prep_kernel<<<14592, 256, 0, stream>>>(ids, emb, xh, Wq, Wk, Wv, Wi, Wo, w16);

    for (int l = 0; l < NLAYER; ++l) {
        _Float16* wl = w16 + (size_t)l * 5 * WS;
        // fused QKV: W rows 0..2303 = Wq|Wk|Wv (contiguous in wl)
        gemm_f16<64><<<1152, 256, 0, stream>>>(
            xh, wl, bq + l*Hdim, bk + l*Hdim, bv + l*Hdim,
            nullptr, qkv, nullptr, 0, F, 0.125f * LOG2E, 64);
        attn_mfma<<<dim3(16, NH, Bb), 256, 0, stream>>>(
            qkv, qkv + F, qkv + 2*F, Op0, Op1, Mp, Lp);
        merge_kernel<<<PL * 4 / 256, 256, 0, stream>>>(Op0, Op1, Mp, Lp, a16, a32);
        gemm_f16<32><<<768, 256, 0, stream>>>(
            a16, wl + 3*WS, bi + l*Hdim, bi + l*Hdim, bi + l*Hdim,
            nullptr, i16, nullptr, 1, 0, 1.f, 128);
        gemm_f16<32><<<768, 256, 0, stream>>>(
            i16, wl + 4*WS, bo + l*Hdim, bo + l*Hdim, bo + l*Hdim,
            a32, xh, (l == NLAYER - 1) ? x32 : nullptr, 0, 0, 1.f, 128);
    }

    cls_kernel<<<Bb * NL, 256, 0, stream>>>(x32, Wc, bc, out);
}